// Round 1
// baseline (2578.013 us; speedup 1.0000x reference)
//
#include <hip/hip_runtime.h>
#include <math.h>

#define NB 10
#define PPC 29          // 3*NB-1
#define CCH 4
#define HID 64
#define HH 256
#define WW 256
#define BB 16
#define TB 1.0f
#define MINW 0.001f
#define MINH 0.001f
#define MIND 0.001f

#define ZTOT (BB*CCH*HH*WW)           // 4194304
#define W2T_FLOATS (CCH*3*HID*3*32)   // 73728 floats = 288 KB in d_ws

__device__ inline unsigned short f2bf(float f) {
    unsigned u = __float_as_uint(f);
    unsigned r = (u + 0x7FFFu + ((u >> 16) & 1u)) >> 16;
    return (unsigned short)r;
}
__device__ inline float bf2f(unsigned short s) {
    return __uint_as_float(((unsigned)s) << 16);
}

__global__ void zero_lad_kernel(float* out) {
    out[ZTOT + threadIdx.x] = 0.0f;
}

// W2 [116][64][3][3] -> w2t [c][ky][ci(64)][kx][j(32 padded)]
__global__ void transpose_w2_kernel(const float* __restrict__ W2, float* __restrict__ w2t) {
    int idx = blockIdx.x * 256 + threadIdx.x;
    if (idx >= W2T_FLOATS) return;
    int j  = idx & 31;
    int t1 = idx >> 5;
    int kx = t1 % 3;
    int t2 = t1 / 3;
    int ci = t2 & 63;
    int t3 = t2 >> 6;
    int ky = t3 % 3;
    int c  = t3 / 3;
    float v = 0.0f;
    if (j < PPC) v = W2[(((c*PPC + j)*HID + ci)*3 + ky)*3 + kx];
    w2t[idx] = v;
}

__global__ __launch_bounds__(256, 2)
void fused_kernel(const float* __restrict__ x, const float* __restrict__ clean,
                  const float* __restrict__ W1, const float* __restrict__ b1,
                  const float* __restrict__ b2, const float* __restrict__ w2t,
                  float* __restrict__ out)
{
    __shared__ unsigned short s_hid[HID * 324];        // 18x18 halo x 64ch bf16 = 41472 B
    __shared__ __align__(16) float s_un[3072];         // union: phaseA clean(1600f) / phaseC w2 chunk(3072f)
    __shared__ float s_red[4];

    const int tid = threadIdx.x;
    const int blk = blockIdx.x;
    const int b   = blk >> 8;
    const int ty  = (blk >> 4) & 15;
    const int tx  = blk & 15;
    const int Y0 = ty * 16, X0 = tx * 16;

    // ---------- Phase A: stage clean tile (4ch x 20 x 20, zero-padded) ----------
    float* s_clean = s_un;
    for (int i = tid; i < 1600; i += 256) {
        int c  = i / 400;
        int r  = i - c * 400;
        int cy = r / 20;
        int cx = r - cy * 20;
        int iy = Y0 - 2 + cy, ix = X0 - 2 + cx;
        float v = 0.0f;
        if (iy >= 0 && iy < HH && ix >= 0 && ix < WW)
            v = clean[((b*CCH + c) << 16) + iy*WW + ix];
        s_clean[i] = v;
    }
    __syncthreads();

    // ---------- Phase B: hid = relu(conv1(clean)) on 18x18 halo, bf16 to LDS ----------
    if (tid < 162) {
        int p0  = tid * 2;              // pixel pair, same row (18 is even)
        int hy  = p0 / 18;
        int hx0 = p0 - hy * 18;         // even
        int iy  = Y0 - 1 + hy;
        int ix0 = X0 - 1 + hx0;
        bool vy = (iy >= 0 && iy < HH);
        bool v0 = vy && (ix0   >= 0 && ix0   < WW);
        bool v1 = vy && (ix0+1 >= 0 && ix0+1 < WW);
        float cwin[4][3][4];
        #pragma unroll
        for (int c = 0; c < 4; ++c)
            #pragma unroll
            for (int ky = 0; ky < 3; ++ky)
                #pragma unroll
                for (int q = 0; q < 4; ++q)
                    cwin[c][ky][q] = s_clean[c*400 + (hy+ky)*20 + hx0 + q];

        for (int co = 0; co < HID; ++co) {
            float wf[36];
            const float4* w1v = (const float4*)(W1 + co*36);   // uniform -> scalar loads
            #pragma unroll
            for (int q = 0; q < 9; ++q) {
                float4 t = w1v[q];
                wf[q*4] = t.x; wf[q*4+1] = t.y; wf[q*4+2] = t.z; wf[q*4+3] = t.w;
            }
            float a0 = b1[co], a1 = a0;
            #pragma unroll
            for (int c = 0; c < 4; ++c)
                #pragma unroll
                for (int ky = 0; ky < 3; ++ky)
                    #pragma unroll
                    for (int kx = 0; kx < 3; ++kx) {
                        float wv = wf[c*9 + ky*3 + kx];
                        a0 += wv * cwin[c][ky][kx];
                        a1 += wv * cwin[c][ky][kx+1];
                    }
            a0 = v0 ? fmaxf(a0, 0.0f) : 0.0f;
            a1 = v1 ? fmaxf(a1, 0.0f) : 0.0f;
            unsigned u0 = f2bf(a0), u1 = f2bf(a1);
            *((unsigned*)&s_hid[co*324 + p0]) = u0 | (u1 << 16);
        }
    }

    // ---------- Phase C: conv2 (per-pixel dot products) + spline ----------
    float local_lad = 0.0f;
    const int py = tid >> 4, px = tid & 15;
    const int iy = Y0 + py, ix = X0 + px;

    for (int c = 0; c < CCH; ++c) {
        float acc[PPC];
        #pragma unroll
        for (int j = 0; j < PPC; ++j) acc[j] = 0.0f;

        for (int ky = 0; ky < 3; ++ky) {
            for (int half = 0; half < 2; ++half) {
                __syncthreads();
                {   // stage contiguous 3072-float chunk from pre-transposed W2
                    const float4* src = (const float4*)(w2t + ((c*3 + ky)*2 + half)*3072);
                    float4* dst = (float4*)s_un;
                    #pragma unroll
                    for (int r = 0; r < 3; ++r)
                        dst[r*256 + tid] = src[r*256 + tid];
                }
                __syncthreads();
                #pragma unroll
                for (int kx = 0; kx < 3; ++kx) {
                    const unsigned short* hrow = &s_hid[(half*32)*324 + (py+ky)*18 + (px+kx)];
                    const float* wrow = s_un + kx*32;
                    #pragma unroll 2
                    for (int ci = 0; ci < 32; ++ci) {
                        float h = bf2f(hrow[ci*324]);
                        const float4* wv = (const float4*)(wrow + ci*96);
                        float4 q0 = wv[0], q1 = wv[1], q2 = wv[2], q3 = wv[3];
                        float4 q4 = wv[4], q5 = wv[5], q6 = wv[6];
                        float q28 = wrow[ci*96 + 28];
                        acc[0]  += h*q0.x; acc[1]  += h*q0.y; acc[2]  += h*q0.z; acc[3]  += h*q0.w;
                        acc[4]  += h*q1.x; acc[5]  += h*q1.y; acc[6]  += h*q1.z; acc[7]  += h*q1.w;
                        acc[8]  += h*q2.x; acc[9]  += h*q2.y; acc[10] += h*q2.z; acc[11] += h*q2.w;
                        acc[12] += h*q3.x; acc[13] += h*q3.y; acc[14] += h*q3.z; acc[15] += h*q3.w;
                        acc[16] += h*q4.x; acc[17] += h*q4.y; acc[18] += h*q4.z; acc[19] += h*q4.w;
                        acc[20] += h*q5.x; acc[21] += h*q5.y; acc[22] += h*q5.z; acc[23] += h*q5.w;
                        acc[24] += h*q6.x; acc[25] += h*q6.y; acc[26] += h*q6.z; acc[27] += h*q6.w;
                        acc[28] += h*q28;
                    }
                }
            }
        }

        // ---------- spline epilogue for channel c ----------
        const float scale = 0.125f;   // 1/sqrt(HIDDEN)
        const float* b2c = b2 + c*PPC;
        float uw[NB], uh[NB], ud9[NB-1];
        #pragma unroll
        for (int j = 0; j < NB; ++j)   uw[j]  = (acc[j]      + b2c[j])      * scale;
        #pragma unroll
        for (int j = 0; j < NB; ++j)   uh[j]  = (acc[NB+j]   + b2c[NB+j])   * scale;
        #pragma unroll
        for (int j = 0; j < NB-1; ++j) ud9[j] =  acc[2*NB+j] + b2c[2*NB+j];

        // softmax widths -> cumw
        float mw = uw[0];
        #pragma unroll
        for (int j = 1; j < NB; ++j) mw = fmaxf(mw, uw[j]);
        float sw = 0.0f;
        #pragma unroll
        for (int j = 0; j < NB; ++j) { uw[j] = expf(uw[j] - mw); sw += uw[j]; }
        float isw = 1.0f / sw;
        float cw[NB+1];
        cw[0] = -TB;
        float run = 0.0f;
        #pragma unroll
        for (int j = 0; j < NB; ++j) {
            float wj = MINW + (1.0f - MINW*NB) * (uw[j] * isw);
            run += wj;
            cw[j+1] = -TB + 2.0f*TB*run;
        }
        cw[NB] = TB;

        // softmax heights -> cumh
        float mh = uh[0];
        #pragma unroll
        for (int j = 1; j < NB; ++j) mh = fmaxf(mh, uh[j]);
        float sh = 0.0f;
        #pragma unroll
        for (int j = 0; j < NB; ++j) { uh[j] = expf(uh[j] - mh); sh += uh[j]; }
        float ish = 1.0f / sh;
        float ch[NB+1];
        ch[0] = -TB;
        float runh = 0.0f;
        #pragma unroll
        for (int j = 0; j < NB; ++j) {
            float hj = MINH + (1.0f - MINH*NB) * (uh[j] * ish);
            runh += hj;
            ch[j+1] = -TB + 2.0f*TB*runh;
        }
        ch[NB] = TB;

        // derivatives (padded ends = 1.0 exactly)
        float dv[NB+1];
        dv[0] = 1.0f; dv[NB] = 1.0f;
        #pragma unroll
        for (int k = 0; k < NB-1; ++k) {
            float v = ud9[k];
            float sp = fmaxf(v, 0.0f) + log1pf(expf(-fabsf(v)));
            dv[k+1] = MIND + sp;
        }

        const int gidx = ((b*CCH + c) << 16) + iy*WW + ix;
        float xv  = x[gidx];
        float xin = fminf(fmaxf(xv, -TB), TB);
        int cnt = 0;
        #pragma unroll
        for (int k = 0; k <= NB; ++k) cnt += (xin >= cw[k]) ? 1 : 0;
        int idx = cnt - 1;
        idx = idx < 0 ? 0 : (idx > NB-1 ? NB-1 : idx);

        float icw = cw[0], inw = cw[1], ich = ch[0], inh = ch[1], d0 = dv[0], d1 = dv[1];
        #pragma unroll
        for (int k = 1; k < NB; ++k) {
            bool m = (idx == k);
            icw = m ? cw[k]   : icw;
            inw = m ? cw[k+1] : inw;
            ich = m ? ch[k]   : ich;
            inh = m ? ch[k+1] : inh;
            d0  = m ? dv[k]   : d0;
            d1  = m ? dv[k+1] : d1;
        }
        float ibw = inw - icw;
        float ihh = inh - ich;
        float idl = ihh / ibw;
        float th  = (xin - icw) / ibw;
        float omt = 1.0f - th;
        float tt  = th * omt;
        float numer = ihh * (idl*th*th + d0*tt);
        float den   = idl + (d0 + d1 - 2.0f*idl)*tt;
        float z_in  = ich + numer/den;
        float dnum  = idl*idl*(d1*th*th + 2.0f*idl*tt + d0*omt*omt);
        float lad_in = logf(dnum) - 2.0f*logf(den);
        bool inside = (xv >= -TB) && (xv <= TB);
        float z = inside ? z_in : xv;
        if (inside) local_lad += lad_in;
        out[gidx] = z;
    }

    // ---------- block-reduce lad, one atomic per block ----------
    #pragma unroll
    for (int off = 32; off >= 1; off >>= 1)
        local_lad += __shfl_xor(local_lad, off, 64);
    __syncthreads();
    if ((tid & 63) == 0) s_red[tid >> 6] = local_lad;
    __syncthreads();
    if (tid == 0) {
        float t = s_red[0] + s_red[1] + s_red[2] + s_red[3];
        atomicAdd(out + ZTOT + b, t);
    }
}

extern "C" void kernel_launch(void* const* d_in, const int* in_sizes, int n_in,
                              void* d_out, int out_size, void* d_ws, size_t ws_size,
                              hipStream_t stream) {
    const float* x     = (const float*)d_in[0];
    const float* clean = (const float*)d_in[1];
    const float* W1    = (const float*)d_in[2];
    const float* b1    = (const float*)d_in[3];
    const float* W2    = (const float*)d_in[4];
    const float* b2    = (const float*)d_in[5];
    float* out = (float*)d_out;
    float* w2t = (float*)d_ws;   // 288 KB scratch

    zero_lad_kernel<<<1, 16, 0, stream>>>(out);
    transpose_w2_kernel<<<(W2T_FLOATS + 255)/256, 256, 0, stream>>>(W2, w2t);
    fused_kernel<<<BB*16*16, 256, 0, stream>>>(x, clean, W1, b1, b2, w2t, out);
}

// Round 4
// 768.500 us; speedup vs baseline: 3.3546x; 3.3546x over previous
//
#include <hip/hip_runtime.h>
#include <math.h>

#define NB 10
#define PPC 29          // 3*NB-1
#define CCH 4
#define HID 64
#define HH 256
#define WW 256
#define BB 16
#define TB 1.0f
#define MINW 0.001f
#define MINH 0.001f
#define MIND 0.001f

#define ZTOT (BB*CCH*HH*WW)     // 4194304

#define HSTR 68                 // s_hid row stride (bf16 elems): 64 + 4 pad, keeps 8B align, 4-way max
#define PSTR 117                // p_buf row stride (f32): odd mod 32 -> conflict-free spline reads
#define NCOLS 116               // valid N columns (PPC*CCH); cols >=116 are padding, never stored/read
#define W2B_ELEMS (18*8*64*8)   // 73728 bf16 per copy; hi+lo copies = 294912 B in d_ws

typedef __attribute__((ext_vector_type(8))) short short8v;
typedef __attribute__((ext_vector_type(4))) short short4v;
typedef __attribute__((ext_vector_type(4))) float f32x4;

__device__ inline unsigned short f2bf(float f) {
    unsigned u = __float_as_uint(f);
    unsigned r = (u + 0x7FFFu + ((u >> 16) & 1u)) >> 16;
    return (unsigned short)r;
}
__device__ inline float bf2f(unsigned short s) {
    return __uint_as_float(((unsigned)s) << 16);
}

__global__ void zero_lad_kernel(float* out) {
    out[ZTOT + threadIdx.x] = 0.0f;
}

// Prepack W2 -> bf16 fragment order, hi/lo split for ~fp32 effective precision.
// w2b[copy(2)][kidx(18)][ntile(8)][lane(64)][j(8)]
// kidx = tap*2 + ks; n = ntile*16 + (lane&15); ci = ks*32 + (lane>>4)*8 + j
__global__ void prepack_w2(const float* __restrict__ W2, unsigned short* __restrict__ w2b) {
    int idx = blockIdx.x * 256 + threadIdx.x;
    if (idx >= W2B_ELEMS) return;
    int j    = idx & 7;
    int lane = (idx >> 3) & 63;
    int nt   = (idx >> 9) & 7;
    int kidx = idx >> 12;            // 0..17
    int tap  = kidx >> 1;
    int ks   = kidx & 1;
    int ky   = tap / 3;
    int kx   = tap - ky * 3;
    int n    = nt * 16 + (lane & 15);
    int ci   = ks * 32 + (lane >> 4) * 8 + j;
    float v = 0.0f;
    if (n < PPC * CCH) v = W2[((n * HID + ci) * 3 + ky) * 3 + kx];
    unsigned short hi = f2bf(v);
    float rem = v - bf2f(hi);
    w2b[idx]             = hi;
    w2b[idx + W2B_ELEMS] = f2bf(rem);
}

__global__ __launch_bounds__(256, 2)
void fused_kernel(const float* __restrict__ x, const float* __restrict__ clean,
                  const float* __restrict__ W1, const float* __restrict__ b1,
                  const float* __restrict__ b2, const unsigned short* __restrict__ w2b,
                  float* __restrict__ out)
{
    __shared__ unsigned short s_hid[324 * HSTR];          // 44064 B, pixel-major bf16
    __shared__ __align__(16) float s_dyn[64 * PSTR];      // 29952 B: clean tile, then p_buf
    __shared__ float s_red[4];

    const int tid  = threadIdx.x;
    const int blk  = blockIdx.x;
    const int b    = blk >> 8;
    const int ty   = (blk >> 4) & 15;
    const int tx   = blk & 15;
    const int Y0 = ty * 16, X0 = tx * 16;

    const int w    = tid >> 6;        // wave id == spline channel c
    const int lane = tid & 63;
    const int l15  = lane & 15;
    const int quad = lane >> 4;
    const int wy   = w >> 1;          // wave M-group (py rows wy*8..wy*8+7)
    const int wx   = w & 1;           // wave N-group (ntiles wx*4..wx*4+3)

    // ---------- Phase A: stage clean tile (4ch x 20 x 20, zero-padded) ----------
    float* s_clean = s_dyn;
    for (int i = tid; i < 1600; i += 256) {
        int c  = i / 400;
        int r  = i - c * 400;
        int cy = r / 20;
        int cx = r - cy * 20;
        int iy = Y0 - 2 + cy, ix = X0 - 2 + cx;
        float v = 0.0f;
        if (iy >= 0 && iy < HH && ix >= 0 && ix < WW)
            v = clean[((b*CCH + c) << 16) + iy*WW + ix];
        s_clean[i] = v;
    }
    __syncthreads();

    // ---------- Phase B: hid = relu(conv1(clean)) on 18x18 halo -> s_hid bf16 ----------
    for (int pass = 0; pass < 2; ++pass) {
        int pix = pass * 256 + tid;
        if (pix < 324) {
            int hy = pix / 18, hx = pix - hy * 18;
            int iy = Y0 - 1 + hy, ix = X0 - 1 + hx;
            bool valid = (iy >= 0 && iy < HH && ix >= 0 && ix < WW);
            float cwin[36];
            #pragma unroll
            for (int c = 0; c < 4; ++c)
                #pragma unroll
                for (int ky = 0; ky < 3; ++ky)
                    #pragma unroll
                    for (int kx = 0; kx < 3; ++kx)
                        cwin[c*9 + ky*3 + kx] = s_clean[c*400 + (hy+ky)*20 + (hx+kx)];
            for (int cog = 0; cog < 8; ++cog) {
                float a8[8];
                #pragma unroll
                for (int coi = 0; coi < 8; ++coi) {
                    int co = cog*8 + coi;
                    const float4* wv = (const float4*)(W1 + co*36);   // uniform -> scalar loads
                    float a = b1[co];
                    #pragma unroll
                    for (int q = 0; q < 9; ++q) {
                        float4 t4 = wv[q];
                        a += t4.x*cwin[q*4] + t4.y*cwin[q*4+1] + t4.z*cwin[q*4+2] + t4.w*cwin[q*4+3];
                    }
                    a8[coi] = valid ? fmaxf(a, 0.0f) : 0.0f;
                }
                unsigned u0 = (unsigned)f2bf(a8[0]) | ((unsigned)f2bf(a8[1]) << 16);
                unsigned u1 = (unsigned)f2bf(a8[2]) | ((unsigned)f2bf(a8[3]) << 16);
                unsigned u2 = (unsigned)f2bf(a8[4]) | ((unsigned)f2bf(a8[5]) << 16);
                unsigned u3 = (unsigned)f2bf(a8[6]) | ((unsigned)f2bf(a8[7]) << 16);
                uint2 p0; p0.x = u0; p0.y = u1;
                uint2 p1; p1.x = u2; p1.y = u3;
                *(uint2*)(&s_hid[pix*HSTR + cog*8])     = p0;   // 8B aligned
                *(uint2*)(&s_hid[pix*HSTR + cog*8 + 4]) = p1;
            }
        }
    }
    __syncthreads();

    // ---------- Phase C: conv2 as implicit GEMM via MFMA (B = W2_hi + W2_lo) ----------
    // M=256 (mtile = py), N=128 (8 ntiles), K=576 (9 taps x 64 ci).
    // Wave (wy,wx): 8 mtiles x 4 ntiles = 32 acc tiles.
    f32x4 acc[8][4];
    #pragma unroll
    for (int mi = 0; mi < 8; ++mi)
        #pragma unroll
        for (int t = 0; t < 4; ++t) {
            acc[mi][t][0] = 0.f; acc[mi][t][1] = 0.f;
            acc[mi][t][2] = 0.f; acc[mi][t][3] = 0.f;
        }

    const short8v* __restrict__ wbv_hi = (const short8v*)w2b;
    const short8v* __restrict__ wbv_lo = (const short8v*)(w2b + W2B_ELEMS);
    const int abase = l15 * HSTR + quad * 8;

    for (int tap = 0; tap < 9; ++tap) {
        int ky = tap / 3;
        int kx = tap - ky * 3;
        int roff = (ky * 18 + kx) * HSTR + abase;
        #pragma unroll
        for (int ks = 0; ks < 2; ++ks) {
            int boff = ((tap*2 + ks)*8 + wx*4)*64 + lane;
            short8v afr[8];
            #pragma unroll
            for (int mi = 0; mi < 8; ++mi) {
                int addr = (wy*8 + mi) * (18*HSTR) + roff + ks*32;
                short4v lo = *(const short4v*)(s_hid + addr);
                short4v hi = *(const short4v*)(s_hid + addr + 4);
                afr[mi] = __builtin_shufflevector(lo, hi, 0, 1, 2, 3, 4, 5, 6, 7);
            }
            short8v bfr[4];
            #pragma unroll
            for (int t = 0; t < 4; ++t)
                bfr[t] = wbv_hi[boff + t*64];
            #pragma unroll
            for (int mi = 0; mi < 8; ++mi)
                #pragma unroll
                for (int t = 0; t < 4; ++t)
                    acc[mi][t] = __builtin_amdgcn_mfma_f32_16x16x32_bf16(
                        afr[mi], bfr[t], acc[mi][t], 0, 0, 0);
            #pragma unroll
            for (int t = 0; t < 4; ++t)
                bfr[t] = wbv_lo[boff + t*64];
            #pragma unroll
            for (int mi = 0; mi < 8; ++mi)
                #pragma unroll
                for (int t = 0; t < 4; ++t)
                    acc[mi][t] = __builtin_amdgcn_mfma_f32_16x16x32_bf16(
                        afr[mi], bfr[t], acc[mi][t], 0, 0, 0);
        }
    }

    // ---------- Epilogue: 4 chunks of 64 pixels through LDS p_buf, then spline ----------
    float* p_buf = s_dyn;                 // 64 x PSTR f32 (clean tile is dead)
    const float* b2c = b2 + w * PPC;      // wave-uniform -> scalar loads
    float lad = 0.0f;

    for (int chunk = 0; chunk < 4; ++chunk) {
        __syncthreads();
        if (wy == (chunk >> 1)) {
            int miB = (chunk & 1) * 4;
            #pragma unroll
            for (int mi2 = 0; mi2 < 4; ++mi2) {
                #pragma unroll
                for (int t = 0; t < 4; ++t) {
                    int col = (wx*4 + t)*16 + l15;
                    if (col < NCOLS) {     // cols >=116 are W2 zero-padding; storing them
                                           // would wrap past PSTR into the next row (R3 bug)
                        f32x4 v = acc[miB + mi2][t];
                        int base = (mi2*16 + quad*4) * PSTR + col;
                        p_buf[base]          = v[0];
                        p_buf[base + PSTR]   = v[1];
                        p_buf[base + 2*PSTR] = v[2];
                        p_buf[base + 3*PSTR] = v[3];
                    }
                }
            }
        }
        __syncthreads();

        // spline: thread -> (c = w, pixel row = lane) of this chunk
        float pv[PPC];
        #pragma unroll
        for (int j = 0; j < PPC; ++j)
            pv[j] = p_buf[lane * PSTR + w * PPC + j];

        const float scale = 0.125f;   // 1/sqrt(HIDDEN)
        float uw[NB], uh[NB], ud9[NB-1];
        #pragma unroll
        for (int j = 0; j < NB; ++j)   uw[j]  = (pv[j]      + b2c[j])      * scale;
        #pragma unroll
        for (int j = 0; j < NB; ++j)   uh[j]  = (pv[NB+j]   + b2c[NB+j])   * scale;
        #pragma unroll
        for (int j = 0; j < NB-1; ++j) ud9[j] =  pv[2*NB+j] + b2c[2*NB+j];

        float mw = uw[0];
        #pragma unroll
        for (int j = 1; j < NB; ++j) mw = fmaxf(mw, uw[j]);
        float sw = 0.0f;
        #pragma unroll
        for (int j = 0; j < NB; ++j) { uw[j] = expf(uw[j] - mw); sw += uw[j]; }
        float isw = 1.0f / sw;
        float cw[NB+1];
        cw[0] = -TB;
        float run = 0.0f;
        #pragma unroll
        for (int j = 0; j < NB; ++j) {
            float wj = MINW + (1.0f - MINW*NB) * (uw[j] * isw);
            run += wj;
            cw[j+1] = -TB + 2.0f*TB*run;
        }
        cw[NB] = TB;

        float mh = uh[0];
        #pragma unroll
        for (int j = 1; j < NB; ++j) mh = fmaxf(mh, uh[j]);
        float sh = 0.0f;
        #pragma unroll
        for (int j = 0; j < NB; ++j) { uh[j] = expf(uh[j] - mh); sh += uh[j]; }
        float ish = 1.0f / sh;
        float chh[NB+1];
        chh[0] = -TB;
        float runh = 0.0f;
        #pragma unroll
        for (int j = 0; j < NB; ++j) {
            float hj = MINH + (1.0f - MINH*NB) * (uh[j] * ish);
            runh += hj;
            chh[j+1] = -TB + 2.0f*TB*runh;
        }
        chh[NB] = TB;

        float dv[NB+1];
        dv[0] = 1.0f; dv[NB] = 1.0f;
        #pragma unroll
        for (int k = 0; k < NB-1; ++k) {
            float v = ud9[k];
            float sp = fmaxf(v, 0.0f) + log1pf(expf(-fabsf(v)));
            dv[k+1] = MIND + sp;
        }

        int iy = Y0 + chunk*4 + quad;
        int ix = X0 + l15;
        int gidx = ((b*CCH + w) << 16) + iy*WW + ix;
        float xv  = x[gidx];
        float xin = fminf(fmaxf(xv, -TB), TB);
        int cnt = 0;
        #pragma unroll
        for (int k = 0; k <= NB; ++k) cnt += (xin >= cw[k]) ? 1 : 0;
        int idx = cnt - 1;
        idx = idx < 0 ? 0 : (idx > NB-1 ? NB-1 : idx);

        float icw = cw[0], inw = cw[1], ich = chh[0], inh = chh[1], d0 = dv[0], d1 = dv[1];
        #pragma unroll
        for (int k = 1; k < NB; ++k) {
            bool m = (idx == k);
            icw = m ? cw[k]    : icw;
            inw = m ? cw[k+1]  : inw;
            ich = m ? chh[k]   : ich;
            inh = m ? chh[k+1] : inh;
            d0  = m ? dv[k]    : d0;
            d1  = m ? dv[k+1]  : d1;
        }
        float ibw = inw - icw;
        float ihh = inh - ich;
        float idl = ihh / ibw;
        float th  = (xin - icw) / ibw;
        float omt = 1.0f - th;
        float tt  = th * omt;
        float numer = ihh * (idl*th*th + d0*tt);
        float den   = idl + (d0 + d1 - 2.0f*idl)*tt;
        float z_in  = ich + numer/den;
        float dnum  = idl*idl*(d1*th*th + 2.0f*idl*tt + d0*omt*omt);
        float lad_in = logf(dnum) - 2.0f*logf(den);
        bool inside = (xv >= -TB) && (xv <= TB);
        float z = inside ? z_in : xv;
        if (inside) lad += lad_in;
        out[gidx] = z;
    }

    // ---------- block-reduce lad, one atomic per block ----------
    #pragma unroll
    for (int off = 32; off >= 1; off >>= 1)
        lad += __shfl_xor(lad, off, 64);
    if (lane == 0) s_red[w] = lad;
    __syncthreads();
    if (tid == 0)
        atomicAdd(out + ZTOT + b, s_red[0] + s_red[1] + s_red[2] + s_red[3]);
}

extern "C" void kernel_launch(void* const* d_in, const int* in_sizes, int n_in,
                              void* d_out, int out_size, void* d_ws, size_t ws_size,
                              hipStream_t stream) {
    const float* x     = (const float*)d_in[0];
    const float* clean = (const float*)d_in[1];
    const float* W1    = (const float*)d_in[2];
    const float* b1    = (const float*)d_in[3];
    const float* W2    = (const float*)d_in[4];
    const float* b2    = (const float*)d_in[5];
    float* out = (float*)d_out;
    unsigned short* w2b = (unsigned short*)d_ws;   // 294912 B (hi + lo copies)

    zero_lad_kernel<<<1, 16, 0, stream>>>(out);
    prepack_w2<<<(W2B_ELEMS + 255)/256, 256, 0, stream>>>(W2, w2b);
    fused_kernel<<<BB*16*16, 256, 0, stream>>>(x, clean, W1, b1, b2, w2b, out);
}

// Round 5
// 490.702 us; speedup vs baseline: 5.2537x; 1.5661x over previous
//
#include <hip/hip_runtime.h>
#include <math.h>

#define NB 10
#define PPC 29          // 3*NB-1
#define CCH 4
#define HID 64
#define HH 256
#define WW 256
#define BB 16
#define TB 1.0f
#define MINW 0.001f
#define MINH 0.001f
#define MIND 0.001f

#define ZTOT (BB*CCH*HH*WW)     // 4194304

// Tile: 16 wide x 8 tall. M=128 pixels, N=128 (116 valid), K=576.
#define TH 8
#define TWD 16
#define HALO_PIX 180            // 10 rows x 18 cols
#define HSTR 68                 // s_hid row stride (bf16): 64 + 4 pad, 8B-aligned rows
#define PSTR 117                // p_buf row stride (f32): odd -> conflict-free spline reads
#define NCOLS 116               // valid N columns; >=116 is zero-padding (never stored)
#define W2B_ELEMS (18*8*64*8)   // 73728 bf16 per copy; hi+lo = 294912 B in d_ws

typedef __attribute__((ext_vector_type(8))) short short8v;
typedef __attribute__((ext_vector_type(4))) short short4v;
typedef __attribute__((ext_vector_type(4))) float f32x4;

__device__ inline unsigned short f2bf(float f) {
    unsigned u = __float_as_uint(f);
    unsigned r = (u + 0x7FFFu + ((u >> 16) & 1u)) >> 16;
    return (unsigned short)r;
}
__device__ inline float bf2f(unsigned short s) {
    return __uint_as_float(((unsigned)s) << 16);
}

__global__ void zero_lad_kernel(float* out) {
    out[ZTOT + threadIdx.x] = 0.0f;
}

// Prepack W2 -> bf16 fragment order, hi/lo split for ~fp32 effective precision.
// w2b[copy(2)][kidx(18)][ntile(8)][lane(64)][j(8)]
// kidx = tap*2 + ks; n = ntile*16 + (lane&15); ci = ks*32 + (lane>>4)*8 + j
__global__ void prepack_w2(const float* __restrict__ W2, unsigned short* __restrict__ w2b) {
    int idx = blockIdx.x * 256 + threadIdx.x;
    if (idx >= W2B_ELEMS) return;
    int j    = idx & 7;
    int lane = (idx >> 3) & 63;
    int nt   = (idx >> 9) & 7;
    int kidx = idx >> 12;            // 0..17
    int tap  = kidx >> 1;
    int ks   = kidx & 1;
    int ky   = tap / 3;
    int kx   = tap - ky * 3;
    int n    = nt * 16 + (lane & 15);
    int ci   = ks * 32 + (lane >> 4) * 8 + j;
    float v = 0.0f;
    if (n < PPC * CCH) v = W2[((n * HID + ci) * 3 + ky) * 3 + kx];
    unsigned short hi = f2bf(v);
    float rem = v - bf2f(hi);
    w2b[idx]             = hi;
    w2b[idx + W2B_ELEMS] = f2bf(rem);
}

__global__ __launch_bounds__(256, 3)
void fused_kernel(const float* __restrict__ x, const float* __restrict__ clean,
                  const float* __restrict__ W1, const float* __restrict__ b1,
                  const float* __restrict__ b2, const unsigned short* __restrict__ w2b,
                  float* __restrict__ out)
{
    // s_un: phase B/C = s_hid (180*HSTR bf16 = 24480 B); epilogue = p_buf (64*117 f32 = 29952 B).
    // Aliasing is barrier-ordered: all MFMA reads of s_hid complete before first p_buf store.
    __shared__ __align__(16) float s_un[64 * PSTR];       // 29952 B
    __shared__ __align__(16) float s_clean[CCH * 12 * 20]; // 3840 B
    __shared__ float s_red[4];

    unsigned short* s_hid = (unsigned short*)s_un;

    const int tid  = threadIdx.x;
    const int blk  = blockIdx.x;
    const int b    = blk >> 9;
    const int ty   = (blk >> 4) & 31;
    const int tx   = blk & 15;
    const int Y0 = ty * TH, X0 = tx * TWD;

    const int w    = tid >> 6;        // wave id == spline channel c
    const int lane = tid & 63;
    const int l15  = lane & 15;
    const int quad = lane >> 4;
    const int wy   = w & 1;           // M half: mtiles wy*4 .. wy*4+3 (pixel rows)
    const int wx   = w >> 1;          // N half: ntiles wx*4 .. wx*4+3

    // ---------- Phase A: stage clean tile (4ch x 12 x 20, zero-padded) ----------
    for (int i = tid; i < CCH*12*20; i += 256) {
        int c  = i / 240;
        int r  = i - c * 240;
        int cy = r / 20;
        int cx = r - cy * 20;
        int iy = Y0 - 2 + cy, ix = X0 - 2 + cx;
        float v = 0.0f;
        if (iy >= 0 && iy < HH && ix >= 0 && ix < WW)
            v = clean[((b*CCH + c) << 16) + iy*WW + ix];
        s_clean[i] = v;
    }
    __syncthreads();

    // ---------- Phase B: hid = relu(conv1(clean)) on 10x18 halo -> s_hid bf16 (one pass) ----------
    if (tid < HALO_PIX) {
        int hy = tid / 18, hx = tid - hy * 18;
        int iy = Y0 - 1 + hy, ix = X0 - 1 + hx;
        bool valid = (iy >= 0 && iy < HH && ix >= 0 && ix < WW);
        float cwin[36];
        #pragma unroll
        for (int c = 0; c < 4; ++c)
            #pragma unroll
            for (int ky = 0; ky < 3; ++ky)
                #pragma unroll
                for (int kx = 0; kx < 3; ++kx)
                    cwin[c*9 + ky*3 + kx] = s_clean[c*240 + (hy+ky)*20 + (hx+kx)];
        for (int cog = 0; cog < 8; ++cog) {
            float a8[8];
            #pragma unroll
            for (int coi = 0; coi < 8; ++coi) {
                int co = cog*8 + coi;
                const float4* wv = (const float4*)(W1 + co*36);   // uniform -> s_load
                float a = b1[co];
                #pragma unroll
                for (int q = 0; q < 9; ++q) {
                    float4 t4 = wv[q];
                    a += t4.x*cwin[q*4] + t4.y*cwin[q*4+1] + t4.z*cwin[q*4+2] + t4.w*cwin[q*4+3];
                }
                a8[coi] = valid ? fmaxf(a, 0.0f) : 0.0f;
            }
            unsigned u0 = (unsigned)f2bf(a8[0]) | ((unsigned)f2bf(a8[1]) << 16);
            unsigned u1 = (unsigned)f2bf(a8[2]) | ((unsigned)f2bf(a8[3]) << 16);
            unsigned u2 = (unsigned)f2bf(a8[4]) | ((unsigned)f2bf(a8[5]) << 16);
            unsigned u3 = (unsigned)f2bf(a8[6]) | ((unsigned)f2bf(a8[7]) << 16);
            uint2 p0; p0.x = u0; p0.y = u1;
            uint2 p1; p1.x = u2; p1.y = u3;
            *(uint2*)(&s_hid[tid*HSTR + cog*8])     = p0;
            *(uint2*)(&s_hid[tid*HSTR + cog*8 + 4]) = p1;
        }
    }
    __syncthreads();

    // ---------- Phase C: conv2 as implicit GEMM via MFMA (B = W2_hi + W2_lo) ----------
    // Wave (wy,wx): 4 mtiles x 4 ntiles = 16 acc tiles (64 f32/thread).
    f32x4 acc[4][4];
    #pragma unroll
    for (int mi = 0; mi < 4; ++mi)
        #pragma unroll
        for (int t = 0; t < 4; ++t) {
            acc[mi][t][0] = 0.f; acc[mi][t][1] = 0.f;
            acc[mi][t][2] = 0.f; acc[mi][t][3] = 0.f;
        }

    const short8v* __restrict__ wbv_hi = (const short8v*)w2b;
    const short8v* __restrict__ wbv_lo = (const short8v*)(w2b + W2B_ELEMS);
    // A addr (shorts): ((wy*4+mi+ky)*18 + l15+kx)*HSTR + quad*8 + ks*32
    const int abase = (wy*4) * (18*HSTR) + l15*HSTR + quad*8;

    for (int tap = 0; tap < 9; ++tap) {
        int ky = tap / 3;
        int kx = tap - ky * 3;
        int roff = abase + ky*(18*HSTR) + kx*HSTR;
        #pragma unroll
        for (int ks = 0; ks < 2; ++ks) {
            int boff = ((tap*2 + ks)*8 + wx*4)*64 + lane;
            short8v afr[4];
            #pragma unroll
            for (int mi = 0; mi < 4; ++mi) {
                int addr = roff + mi*(18*HSTR) + ks*32;
                short4v lo = *(const short4v*)(s_hid + addr);
                short4v hi = *(const short4v*)(s_hid + addr + 4);
                afr[mi] = __builtin_shufflevector(lo, hi, 0, 1, 2, 3, 4, 5, 6, 7);
            }
            short8v bfr[4];
            #pragma unroll
            for (int t = 0; t < 4; ++t)
                bfr[t] = wbv_hi[boff + t*64];
            #pragma unroll
            for (int mi = 0; mi < 4; ++mi)
                #pragma unroll
                for (int t = 0; t < 4; ++t)
                    acc[mi][t] = __builtin_amdgcn_mfma_f32_16x16x32_bf16(
                        afr[mi], bfr[t], acc[mi][t], 0, 0, 0);
            #pragma unroll
            for (int t = 0; t < 4; ++t)
                bfr[t] = wbv_lo[boff + t*64];
            #pragma unroll
            for (int mi = 0; mi < 4; ++mi)
                #pragma unroll
                for (int t = 0; t < 4; ++t)
                    acc[mi][t] = __builtin_amdgcn_mfma_f32_16x16x32_bf16(
                        afr[mi], bfr[t], acc[mi][t], 0, 0, 0);
        }
    }

    // ---------- Epilogue: 2 chunks of 64 pixels through LDS p_buf (aliases s_hid), then spline ----------
    float* p_buf = s_un;
    const float* b2c = b2 + w * PPC;      // wave-uniform -> scalar loads
    float lad = 0.0f;

    for (int chunk = 0; chunk < 2; ++chunk) {
        __syncthreads();   // chunk 0: all s_hid MFMA reads done; chunk 1: chunk-0 spline reads done
        if (wy == chunk) {
            #pragma unroll
            for (int mi = 0; mi < 4; ++mi) {
                #pragma unroll
                for (int t = 0; t < 4; ++t) {
                    int col = (wx*4 + t)*16 + l15;
                    if (col < NCOLS) {    // cols >=116 are padding; would wrap PSTR (R3 bug)
                        f32x4 v = acc[mi][t];
                        int base = (mi*16 + quad*4) * PSTR + col;
                        p_buf[base]          = v[0];
                        p_buf[base + PSTR]   = v[1];
                        p_buf[base + 2*PSTR] = v[2];
                        p_buf[base + 3*PSTR] = v[3];
                    }
                }
            }
        }
        __syncthreads();

        // spline: thread -> (c = w, chunk-local pixel = lane)
        float pv[PPC];
        #pragma unroll
        for (int j = 0; j < PPC; ++j)
            pv[j] = p_buf[lane * PSTR + w * PPC + j];

        const float scale = 0.125f;   // 1/sqrt(HIDDEN)
        float uw[NB], uh[NB], ud9[NB-1];
        #pragma unroll
        for (int j = 0; j < NB; ++j)   uw[j]  = (pv[j]      + b2c[j])      * scale;
        #pragma unroll
        for (int j = 0; j < NB; ++j)   uh[j]  = (pv[NB+j]   + b2c[NB+j])   * scale;
        #pragma unroll
        for (int j = 0; j < NB-1; ++j) ud9[j] =  pv[2*NB+j] + b2c[2*NB+j];

        float mw = uw[0];
        #pragma unroll
        for (int j = 1; j < NB; ++j) mw = fmaxf(mw, uw[j]);
        float sw = 0.0f;
        #pragma unroll
        for (int j = 0; j < NB; ++j) { uw[j] = __expf(uw[j] - mw); sw += uw[j]; }
        float isw = 1.0f / sw;
        float cw[NB+1];
        cw[0] = -TB;
        float run = 0.0f;
        #pragma unroll
        for (int j = 0; j < NB; ++j) {
            float wj = MINW + (1.0f - MINW*NB) * (uw[j] * isw);
            run += wj;
            cw[j+1] = -TB + 2.0f*TB*run;
        }
        cw[NB] = TB;

        float mh = uh[0];
        #pragma unroll
        for (int j = 1; j < NB; ++j) mh = fmaxf(mh, uh[j]);
        float sh = 0.0f;
        #pragma unroll
        for (int j = 0; j < NB; ++j) { uh[j] = __expf(uh[j] - mh); sh += uh[j]; }
        float ish = 1.0f / sh;
        float chh[NB+1];
        chh[0] = -TB;
        float runh = 0.0f;
        #pragma unroll
        for (int j = 0; j < NB; ++j) {
            float hj = MINH + (1.0f - MINH*NB) * (uh[j] * ish);
            runh += hj;
            chh[j+1] = -TB + 2.0f*TB*runh;
        }
        chh[NB] = TB;

        float dv[NB+1];
        dv[0] = 1.0f; dv[NB] = 1.0f;
        #pragma unroll
        for (int k = 0; k < NB-1; ++k) {
            float v = ud9[k];
            // softplus(v) = max(v,0) + log(1+exp(-|v|)); fast intrinsics are safe:
            // exp(-|v|) tiny -> 1+t rounds to 1 -> log 0, matching log1p asymptote
            float sp = fmaxf(v, 0.0f) + __logf(1.0f + __expf(-fabsf(v)));
            dv[k+1] = MIND + sp;
        }

        int iy = Y0 + chunk*4 + quad;
        int ix = X0 + l15;
        int gidx = ((b*CCH + w) << 16) + iy*WW + ix;
        float xv  = x[gidx];
        float xin = fminf(fmaxf(xv, -TB), TB);
        int cnt = 0;
        #pragma unroll
        for (int k = 0; k <= NB; ++k) cnt += (xin >= cw[k]) ? 1 : 0;
        int idx = cnt - 1;
        idx = idx < 0 ? 0 : (idx > NB-1 ? NB-1 : idx);

        float icw = cw[0], inw = cw[1], ich = chh[0], inh = chh[1], d0 = dv[0], d1 = dv[1];
        #pragma unroll
        for (int k = 1; k < NB; ++k) {
            bool m = (idx == k);
            icw = m ? cw[k]    : icw;
            inw = m ? cw[k+1]  : inw;
            ich = m ? chh[k]   : ich;
            inh = m ? chh[k+1] : inh;
            d0  = m ? dv[k]    : d0;
            d1  = m ? dv[k+1]  : d1;
        }
        float ibw = inw - icw;
        float ihh = inh - ich;
        float idl = ihh / ibw;
        float th  = (xin - icw) / ibw;
        float omt = 1.0f - th;
        float tt  = th * omt;
        float numer = ihh * (idl*th*th + d0*tt);
        float den   = idl + (d0 + d1 - 2.0f*idl)*tt;
        float z_in  = ich + numer/den;
        float dnum  = idl*idl*(d1*th*th + 2.0f*idl*tt + d0*omt*omt);
        float lad_in = __logf(dnum) - 2.0f*__logf(den);
        bool inside = (xv >= -TB) && (xv <= TB);
        float z = inside ? z_in : xv;
        if (inside) lad += lad_in;
        out[gidx] = z;
    }

    // ---------- block-reduce lad, one atomic per block ----------
    #pragma unroll
    for (int off = 32; off >= 1; off >>= 1)
        lad += __shfl_xor(lad, off, 64);
    if (lane == 0) s_red[w] = lad;
    __syncthreads();
    if (tid == 0)
        atomicAdd(out + ZTOT + b, s_red[0] + s_red[1] + s_red[2] + s_red[3]);
}

extern "C" void kernel_launch(void* const* d_in, const int* in_sizes, int n_in,
                              void* d_out, int out_size, void* d_ws, size_t ws_size,
                              hipStream_t stream) {
    const float* x     = (const float*)d_in[0];
    const float* clean = (const float*)d_in[1];
    const float* W1    = (const float*)d_in[2];
    const float* b1    = (const float*)d_in[3];
    const float* W2    = (const float*)d_in[4];
    const float* b2    = (const float*)d_in[5];
    float* out = (float*)d_out;
    unsigned short* w2b = (unsigned short*)d_ws;   // 294912 B (hi + lo copies)

    zero_lad_kernel<<<1, 16, 0, stream>>>(out);
    prepack_w2<<<(W2B_ELEMS + 255)/256, 256, 0, stream>>>(W2, w2b);
    fused_kernel<<<BB*32*16, 256, 0, stream>>>(x, clean, W1, b1, b2, w2b, out);
}